// Round 8
// baseline (539.490 us; speedup 1.0000x reference)
//
#include <hip/hip_runtime.h>

#define FP8_MAX_F 448.0f

static constexpr int M = 8192;   // 4*2048
static constexpr int N = 8192;
static constexpr int K = 4096;

typedef __attribute__((ext_vector_type(4))) int i32x4;

#define AS1 __attribute__((address_space(1)))
#define AS3 __attribute__((address_space(3)))
#define BARRIER() asm volatile("s_barrier" ::: "memory")
#define VMCNT(n)  asm volatile("s_waitcnt vmcnt(" #n ")" ::: "memory")

// ---------------- amax over both tensors (exact, bit-trick atomicMax) --------
__global__ void amax_kernel(const float* __restrict__ x, const float* __restrict__ w,
                            unsigned* __restrict__ out) {
    const long n4x = (long)M * K / 4;
    const long n4t = n4x + (long)N * K / 4;
    unsigned lx = 0u, lw = 0u;
    const long stride = (long)gridDim.x * blockDim.x;
    for (long i = (long)blockIdx.x * blockDim.x + threadIdx.x; i < n4t; i += stride) {
        if (i < n4x) {
            float4 v = ((const float4*)x)[i];
            unsigned a0 = __float_as_uint(v.x) & 0x7fffffffu;
            unsigned a1 = __float_as_uint(v.y) & 0x7fffffffu;
            unsigned a2 = __float_as_uint(v.z) & 0x7fffffffu;
            unsigned a3 = __float_as_uint(v.w) & 0x7fffffffu;
            lx = max(lx, max(max(a0, a1), max(a2, a3)));
        } else {
            float4 v = ((const float4*)w)[i - n4x];
            unsigned a0 = __float_as_uint(v.x) & 0x7fffffffu;
            unsigned a1 = __float_as_uint(v.y) & 0x7fffffffu;
            unsigned a2 = __float_as_uint(v.z) & 0x7fffffffu;
            unsigned a3 = __float_as_uint(v.w) & 0x7fffffffu;
            lw = max(lw, max(max(a0, a1), max(a2, a3)));
        }
    }
    #pragma unroll
    for (int off = 32; off > 0; off >>= 1) {
        lx = max(lx, (unsigned)__shfl_down((int)lx, off, 64));
        lw = max(lw, (unsigned)__shfl_down((int)lw, off, 64));
    }
    __shared__ unsigned smx[4], smw[4];
    if ((threadIdx.x & 63) == 0) { smx[threadIdx.x >> 6] = lx; smw[threadIdx.x >> 6] = lw; }
    __syncthreads();
    if (threadIdx.x == 0) {
        atomicMax(&out[0], max(max(smx[0], smx[1]), max(smx[2], smx[3])));
        atomicMax(&out[1], max(max(smw[0], smw[1]), max(smw[2], smw[3])));
    }
}

// ---------------- quantize both tensors to int8 codes, pre-swizzled layout ---
// Logical code (row r, k) stored with its 16B chunk XOR-permuted within each
// 64B k-group: chunk' = (k>>4)&3 XOR ((r>>1)&3). GEMM stages linearly
// (global_load_lds) and applies the same XOR on ds_read (T2, rule 21).
__device__ __forceinline__ signed char quant1(float v, float s) {
    float f = fminf(fmaxf(v * s, -FP8_MAX_F), FP8_MAX_F);
    return (signed char)(int)rintf(f / FP8_MAX_F * 127.0f);
}

__global__ void quant_kernel(const float* __restrict__ x, const float* __restrict__ w,
                             signed char* __restrict__ qx, signed char* __restrict__ qw,
                             const unsigned* __restrict__ amax_bits) {
    const float ax = fmaxf(__uint_as_float(amax_bits[0]), 1e-12f);
    const float aw = fmaxf(__uint_as_float(amax_bits[1]), 1e-12f);
    const float sxv = FP8_MAX_F / ax;
    const float swv = FP8_MAX_F / aw;
    const long cx = (long)M * K / 16;
    const long ct = cx + (long)N * K / 16;
    const long stride = (long)gridDim.x * blockDim.x;
    for (long ci = (long)blockIdx.x * blockDim.x + threadIdx.x; ci < ct; ci += stride) {
        const float* src; signed char* dst; float s; long c;
        if (ci < cx) { src = x; dst = qx; s = sxv; c = ci; }
        else         { src = w; dst = qw; s = swv; c = ci - cx; }
        const long r = c >> 8;              // K/16 = 256 chunks per row
        const int  cr = (int)(c & 255);
        const float4* in = (const float4*)(src + r * K + cr * 16);
        signed char ob[16];
        #pragma unroll
        for (int j = 0; j < 4; ++j) {
            float4 v = in[j];
            ob[j * 4 + 0] = quant1(v.x, s);
            ob[j * 4 + 1] = quant1(v.y, s);
            ob[j * 4 + 2] = quant1(v.z, s);
            ob[j * 4 + 3] = quant1(v.w, s);
        }
        const int osub = (cr & 3) ^ ((int)(r >> 1) & 3);
        *(int4*)(dst + r * K + ((long)((cr & ~3) + osub)) * 16) = *(const int4*)ob;
    }
}

// ---------------- int8 GEMM: C[m][n] = sum_k A[m][k]*B[n][k] ----------------
// 256x256 tile, BK=64, 512 threads = 8 waves (2M x 4N), wave output 128x64.
// R3 schedule (4-deep LDS, frags prefetched 1 tile ahead, 4 barriers/tile,
// counted vmcnt(4), setprio, T2 swizzle). Addressing discipline:
//  - flat LDS, 4-unrolled loop -> ds_read = vaddr + literal offset
//  - staging via 4 per-lane base pointers bumped +64B/tile
//  - global_load_lds offset arg ALWAYS 0 (R7 proved nonzero offset arg is
//    NOT "global addr + N" on gfx950 -> silent corruption)
__global__ __launch_bounds__(512, 2) void gemm_i8_kernel(
    const signed char* __restrict__ Aq, const signed char* __restrict__ Bq,
    float* __restrict__ C, const unsigned* __restrict__ amax_bits)
{
    __shared__ signed char lds[131072];   // A: [0,64K) 4x16K, B: [64K,128K) 4x16K

    const int tid  = threadIdx.x;
    const int wid  = tid >> 6;
    const int lane = tid & 63;
    const int wm = wid >> 2;          // 0..1  (M half)
    const int wn = wid & 3;           // 0..3  (N quarter)
    const int fr = lane & 15;
    const int fq = lane >> 4;

    const long row0 = (long)blockIdx.x * 256;
    const long col0 = (long)blockIdx.y * 256;

    // staging: one issue = 512 thr x 16B = 128 rows x 64B (linear LDS dest)
    const long stag_off = (long)(tid >> 2) * K + (long)(tid & 3) * 16;
    const signed char* ga0 = Aq + row0 * K + stag_off;
    const signed char* ga1 = ga0 + 128L * K;
    const signed char* gb0 = Bq + col0 * K + stag_off;
    const signed char* gb1 = gb0 + 128L * K;

    // swizzled ds_read offsets (XOR constant across mi/ni: steps are x16 rows)
    const int arow = wm * 128 + fr;
    const int aoff = arow * 64 + ((fq ^ ((arow >> 1) & 3)) * 16);
    const int brow = wn * 64 + fr;
    const int boff = 65536 + brow * 64 + ((fq ^ ((brow >> 1) & 3)) * 16);

    i32x4 acc[8][4] = {};
    i32x4 afR[2][8];      // parity-double-buffered A fragments
    i32x4 bR[2][4];       // parity-double-buffered B fragments

#define SA(BUF) do { \
        __builtin_amdgcn_global_load_lds((const AS1 void*)ga0, \
            (AS3 void*)&lds[(BUF) * 16384 + wid * 1024], 16, 0, 0); \
        __builtin_amdgcn_global_load_lds((const AS1 void*)ga1, \
            (AS3 void*)&lds[(BUF) * 16384 + 8192 + wid * 1024], 16, 0, 0); \
    } while (0)

#define SB(BUF) do { \
        __builtin_amdgcn_global_load_lds((const AS1 void*)gb0, \
            (AS3 void*)&lds[65536 + (BUF) * 16384 + wid * 1024], 16, 0, 0); \
        __builtin_amdgcn_global_load_lds((const AS1 void*)gb1, \
            (AS3 void*)&lds[65536 + (BUF) * 16384 + 8192 + wid * 1024], 16, 0, 0); \
    } while (0)

#define BUMP() do { ga0 += 64; ga1 += 64; gb0 += 64; gb1 += 64; } while (0)
#define SBB(BUF) do { SB(BUF); BUMP(); } while (0)

#define MFMA_HALF(CUR, N0, N1) do { \
        BARRIER(); \
        __builtin_amdgcn_s_setprio(1); \
        _Pragma("unroll") \
        for (int mi = 0; mi < 8; ++mi) { \
            acc[mi][N0] = __builtin_amdgcn_mfma_i32_16x16x64_i8( \
                afR[CUR][mi], bR[CUR][N0], acc[mi][N0], 0, 0, 0); \
            acc[mi][N1] = __builtin_amdgcn_mfma_i32_16x16x64_i8( \
                afR[CUR][mi], bR[CUR][N1], acc[mi][N1], 0, 0, 0); \
        } \
        __builtin_amdgcn_s_setprio(0); \
        BARRIER(); \
    } while (0)

    // NB = buf of tile t+1 (literal); CUR/NXT = reg parity (literals).
#define TILE(NB, CUR, NXT, SA_STMT, SB_STMT, VM_STMT, DO_RD) do { \
        if (DO_RD) { \
            _Pragma("unroll") \
            for (int mi = 0; mi < 8; ++mi) \
                afR[NXT][mi] = *(const i32x4*)&lds[(NB) * 16384 + aoff + mi * 1024]; \
        } \
        SA_STMT; \
        MFMA_HALF(CUR, 0, 1); \
        if (DO_RD) { \
            _Pragma("unroll") \
            for (int ni = 0; ni < 4; ++ni) \
                bR[NXT][ni] = *(const i32x4*)&lds[(NB) * 16384 + boff + ni * 1024]; \
        } \
        SB_STMT; \
        VM_STMT; \
        MFMA_HALF(CUR, 2, 3); \
    } while (0)

    // prologue: stage tiles 0,1,2 (12 issues/wave); drain to 4 -> 0,1 resident
    SA(0); SBB(0);
    SA(1); SBB(1);
    SA(2); SBB(2);           // pointers now at tile 3
    VMCNT(4);
    BARRIER();
    #pragma unroll
    for (int mi = 0; mi < 8; ++mi)
        afR[0][mi] = *(const i32x4*)&lds[aoff + mi * 1024];
    #pragma unroll
    for (int ni = 0; ni < 4; ++ni)
        bR[0][ni] = *(const i32x4*)&lds[boff + ni * 1024];

    // main loop: tiles 0..55, staging tiles 3..58 (pointer carries tile idx)
    #pragma unroll 1
    for (int t = 0; t < 56; t += 4) {
        TILE(1, 0, 1, SA(3), SBB(3), VMCNT(4), 1);
        TILE(2, 1, 0, SA(0), SBB(0), VMCNT(4), 1);
        TILE(3, 0, 1, SA(1), SBB(1), VMCNT(4), 1);
        TILE(0, 1, 0, SA(2), SBB(2), VMCNT(4), 1);
    }
    // tail: tiles 56..63 (stages 59..63, then vmcnt ladder 4 -> 0)
    TILE(1, 0, 1, SA(3), SBB(3), VMCNT(4), 1);   // t=56 stage 59
    TILE(2, 1, 0, SA(0), SBB(0), VMCNT(4), 1);   // t=57 stage 60
    TILE(3, 0, 1, SA(1), SBB(1), VMCNT(4), 1);   // t=58 stage 61
    TILE(0, 1, 0, SA(2), SBB(2), VMCNT(4), 1);   // t=59 stage 62
    TILE(1, 0, 1, SA(3), SBB(3), VMCNT(4), 1);   // t=60 stage 63
    TILE(2, 1, 0, (void)0, (void)0, VMCNT(0), 1);   // t=61
    TILE(3, 0, 1, (void)0, (void)0, (void)0,  1);   // t=62
    TILE(0, 1, 0, (void)0, (void)0, (void)0,  0);   // t=63

#undef TILE
#undef MFMA_HALF
#undef SBB
#undef BUMP
#undef SB
#undef SA

    const float ax = fmaxf(__uint_as_float(amax_bits[0]), 1e-12f);
    const float aw = fmaxf(__uint_as_float(amax_bits[1]), 1e-12f);
    const float factor = ax * aw * (1.0f / (127.0f * 127.0f));

    #pragma unroll
    for (int mi = 0; mi < 8; ++mi) {
        #pragma unroll
        for (int ni = 0; ni < 4; ++ni) {
            const long col = col0 + wn * 64 + ni * 16 + fr;
            #pragma unroll
            for (int j = 0; j < 4; ++j) {
                const long row = row0 + wm * 128 + mi * 16 + fq * 4 + j;
                C[row * N + col] = (float)acc[mi][ni][j] * factor;
            }
        }
    }
}

extern "C" void kernel_launch(void* const* d_in, const int* in_sizes, int n_in,
                              void* d_out, int out_size, void* d_ws, size_t ws_size,
                              hipStream_t stream) {
    const float* x = (const float*)d_in[0];   // [4,2048,4096] -> [M,K]
    const float* w = (const float*)d_in[1];   // [N,K]
    float* out = (float*)d_out;               // [M,N]

    unsigned char* ws = (unsigned char*)d_ws;
    unsigned* amax = (unsigned*)ws;                        // 2 uints
    signed char* aq = (signed char*)(ws + 256);            // M*K int8 (swizzled)
    signed char* wq = aq + (long)M * K;                    // N*K int8 (swizzled)

    hipMemsetAsync(amax, 0, 2 * sizeof(unsigned), stream);
    amax_kernel<<<2048, 256, 0, stream>>>(x, w, amax);
    quant_kernel<<<4096, 256, 0, stream>>>(x, w, aq, wq, amax);

    dim3 grid(M / 256, N / 256);
    gemm_i8_kernel<<<grid, 512, 0, stream>>>(aq, wq, out, amax);
}

// Round 9
// 465.904 us; speedup vs baseline: 1.1579x; 1.1579x over previous
//
#include <hip/hip_runtime.h>

#define FP8_MAX_F 448.0f

static constexpr int M = 8192;   // 4*2048
static constexpr int N = 8192;
static constexpr int K = 4096;

typedef __attribute__((ext_vector_type(4))) int i32x4;

#define AS1 __attribute__((address_space(1)))
#define AS3 __attribute__((address_space(3)))
#define BARRIER() asm volatile("s_barrier" ::: "memory")
#define VMCNT(n)  asm volatile("s_waitcnt vmcnt(" #n ")" ::: "memory")

// ---------------- amax over both tensors (exact, bit-trick atomicMax) --------
__global__ void amax_kernel(const float* __restrict__ x, const float* __restrict__ w,
                            unsigned* __restrict__ out) {
    const long n4x = (long)M * K / 4;
    const long n4t = n4x + (long)N * K / 4;
    unsigned lx = 0u, lw = 0u;
    const long stride = (long)gridDim.x * blockDim.x;
    for (long i = (long)blockIdx.x * blockDim.x + threadIdx.x; i < n4t; i += stride) {
        if (i < n4x) {
            float4 v = ((const float4*)x)[i];
            unsigned a0 = __float_as_uint(v.x) & 0x7fffffffu;
            unsigned a1 = __float_as_uint(v.y) & 0x7fffffffu;
            unsigned a2 = __float_as_uint(v.z) & 0x7fffffffu;
            unsigned a3 = __float_as_uint(v.w) & 0x7fffffffu;
            lx = max(lx, max(max(a0, a1), max(a2, a3)));
        } else {
            float4 v = ((const float4*)w)[i - n4x];
            unsigned a0 = __float_as_uint(v.x) & 0x7fffffffu;
            unsigned a1 = __float_as_uint(v.y) & 0x7fffffffu;
            unsigned a2 = __float_as_uint(v.z) & 0x7fffffffu;
            unsigned a3 = __float_as_uint(v.w) & 0x7fffffffu;
            lw = max(lw, max(max(a0, a1), max(a2, a3)));
        }
    }
    #pragma unroll
    for (int off = 32; off > 0; off >>= 1) {
        lx = max(lx, (unsigned)__shfl_down((int)lx, off, 64));
        lw = max(lw, (unsigned)__shfl_down((int)lw, off, 64));
    }
    __shared__ unsigned smx[4], smw[4];
    if ((threadIdx.x & 63) == 0) { smx[threadIdx.x >> 6] = lx; smw[threadIdx.x >> 6] = lw; }
    __syncthreads();
    if (threadIdx.x == 0) {
        atomicMax(&out[0], max(max(smx[0], smx[1]), max(smx[2], smx[3])));
        atomicMax(&out[1], max(max(smw[0], smw[1]), max(smw[2], smw[3])));
    }
}

// ---------------- quantize both tensors to int8 codes, pre-swizzled layout ---
// Logical code (row r, k) stored with its 16B chunk XOR-permuted within each
// 64B k-group: chunk' = (k>>4)&3 XOR ((r>>1)&3). GEMM stages linearly
// (global_load_lds) and applies the same XOR on ds_read (T2, rule 21).
__device__ __forceinline__ signed char quant1(float v, float s) {
    float f = fminf(fmaxf(v * s, -FP8_MAX_F), FP8_MAX_F);
    return (signed char)(int)rintf(f / FP8_MAX_F * 127.0f);
}

__global__ void quant_kernel(const float* __restrict__ x, const float* __restrict__ w,
                             signed char* __restrict__ qx, signed char* __restrict__ qw,
                             const unsigned* __restrict__ amax_bits) {
    const float ax = fmaxf(__uint_as_float(amax_bits[0]), 1e-12f);
    const float aw = fmaxf(__uint_as_float(amax_bits[1]), 1e-12f);
    const float sxv = FP8_MAX_F / ax;
    const float swv = FP8_MAX_F / aw;
    const long cx = (long)M * K / 16;
    const long ct = cx + (long)N * K / 16;
    const long stride = (long)gridDim.x * blockDim.x;
    for (long ci = (long)blockIdx.x * blockDim.x + threadIdx.x; ci < ct; ci += stride) {
        const float* src; signed char* dst; float s; long c;
        if (ci < cx) { src = x; dst = qx; s = sxv; c = ci; }
        else         { src = w; dst = qw; s = swv; c = ci - cx; }
        const long r = c >> 8;              // K/16 = 256 chunks per row
        const int  cr = (int)(c & 255);
        const float4* in = (const float4*)(src + r * K + cr * 16);
        signed char ob[16];
        #pragma unroll
        for (int j = 0; j < 4; ++j) {
            float4 v = in[j];
            ob[j * 4 + 0] = quant1(v.x, s);
            ob[j * 4 + 1] = quant1(v.y, s);
            ob[j * 4 + 2] = quant1(v.z, s);
            ob[j * 4 + 3] = quant1(v.w, s);
        }
        const int osub = (cr & 3) ^ ((int)(r >> 1) & 3);
        *(int4*)(dst + r * K + ((long)((cr & ~3) + osub)) * 16) = *(const int4*)ob;
    }
}

// ---------------- int8 GEMM: C[m][n] = sum_k A[m][k]*B[n][k] ----------------
// 128x256 tile, BK=64, 512 threads = 8 waves (2M x 4N), wave output 64x64
// (acc = 64 VGPR). 2-deep LDS (48KB) + __launch_bounds__(512,4) -> TWO
// blocks/CU, 4 waves/SIMD: block A's stage/vmcnt/barrier windows overlap
// block B's MFMA bursts (m114 cross-block TLP — the mechanism our 1-block
// 128KB designs lacked; 5 schedule variants all plateaued 42-50%).
// Schedule = T3 minimum 2-phase: STAGE(t+1) -> READ(t) -> MFMA -> vmcnt(0)
// -> barrier (one barrier/tile). T2 swizzled ds_read, setprio (T5).
__global__ __launch_bounds__(512, 4) void gemm_i8_kernel(
    const signed char* __restrict__ Aq, const signed char* __restrict__ Bq,
    float* __restrict__ C, const unsigned* __restrict__ amax_bits)
{
    // [buf][ A: 0..8K, B: 8K..24K ]
    __shared__ signed char lds[2][24576];

    const int tid  = threadIdx.x;
    const int wid  = tid >> 6;
    const int lane = tid & 63;
    const int wm = wid >> 2;          // 0..1  (M half: 64 rows)
    const int wn = wid & 3;           // 0..3  (N quarter: 64 cols)
    const int fr = lane & 15;
    const int fq = lane >> 4;

    const long row0 = (long)blockIdx.x * 128;
    const long col0 = (long)blockIdx.y * 256;

    // staging: A tile (128 rows x 64B) = ONE issue (512 thr x 16B);
    // B tile (256 rows) = two issues. Linear LDS dest (wave base + lane*16).
    const long stag_row = tid >> 2;                 // 0..127
    const long stag_col = (long)(tid & 3) * 16;     // 0,16,32,48
    const signed char* ga  = Aq + (row0 + stag_row) * K + stag_col;
    const signed char* gb0 = Bq + (col0 + stag_row) * K + stag_col;
    const signed char* gb1 = gb0 + 128L * K;

    // swizzled ds_read offsets; XOR term (fq ^ ((fr>>1)&3)) constant per lane
    const int sx = (fq ^ ((fr >> 1) & 3)) * 16;
    const int aoff = (wm * 64 + fr) * 64 + sx;           // + mi*1024
    const int boff = 8192 + (wn * 64 + fr) * 64 + sx;    // + ni*1024

    i32x4 acc[4][4] = {};

#define STAGE(B) do { \
        __builtin_amdgcn_global_load_lds((const AS1 void*)ga, \
            (AS3 void*)&lds[B][wid * 1024], 16, 0, 0); \
        __builtin_amdgcn_global_load_lds((const AS1 void*)gb0, \
            (AS3 void*)&lds[B][8192 + wid * 1024], 16, 0, 0); \
        __builtin_amdgcn_global_load_lds((const AS1 void*)gb1, \
            (AS3 void*)&lds[B][16384 + wid * 1024], 16, 0, 0); \
        ga += 64; gb0 += 64; gb1 += 64; \
    } while (0)

    // TILE: stage next (if any), read current frags, MFMA, drain, barrier
#define TILE(B, STAGE_STMT, VM_STMT) do { \
        STAGE_STMT; \
        i32x4 af[4], bf[4]; \
        _Pragma("unroll") \
        for (int mi = 0; mi < 4; ++mi) \
            af[mi] = *(const i32x4*)&lds[B][aoff + mi * 1024]; \
        _Pragma("unroll") \
        for (int ni = 0; ni < 4; ++ni) \
            bf[ni] = *(const i32x4*)&lds[B][boff + ni * 1024]; \
        __builtin_amdgcn_s_setprio(1); \
        _Pragma("unroll") \
        for (int mi = 0; mi < 4; ++mi) \
            _Pragma("unroll") \
            for (int ni = 0; ni < 4; ++ni) \
                acc[mi][ni] = __builtin_amdgcn_mfma_i32_16x16x64_i8( \
                    af[mi], bf[ni], acc[mi][ni], 0, 0, 0); \
        __builtin_amdgcn_s_setprio(0); \
        VM_STMT; \
        BARRIER(); \
    } while (0)

    // prologue: stage tile 0, drain, barrier
    STAGE(0);
    VMCNT(0);
    BARRIER();

    // main loop: 2 tiles/iter for literal buffer indices (K/64 = 64 tiles)
    #pragma unroll 1
    for (int t = 0; t < 62; t += 2) {
        TILE(0, STAGE(1), VMCNT(0));
        TILE(1, STAGE(0), VMCNT(0));
    }
    TILE(0, STAGE(1), VMCNT(0));   // t=62, stage 63
    TILE(1, (void)0,  (void)0);    // t=63

#undef TILE
#undef STAGE

    const float ax = fmaxf(__uint_as_float(amax_bits[0]), 1e-12f);
    const float aw = fmaxf(__uint_as_float(amax_bits[1]), 1e-12f);
    const float factor = ax * aw * (1.0f / (127.0f * 127.0f));

    #pragma unroll
    for (int mi = 0; mi < 4; ++mi) {
        #pragma unroll
        for (int ni = 0; ni < 4; ++ni) {
            const long col = col0 + wn * 64 + ni * 16 + fr;
            #pragma unroll
            for (int j = 0; j < 4; ++j) {
                const long row = row0 + wm * 64 + mi * 16 + fq * 4 + j;
                C[row * N + col] = (float)acc[mi][ni][j] * factor;
            }
        }
    }
}

extern "C" void kernel_launch(void* const* d_in, const int* in_sizes, int n_in,
                              void* d_out, int out_size, void* d_ws, size_t ws_size,
                              hipStream_t stream) {
    const float* x = (const float*)d_in[0];   // [4,2048,4096] -> [M,K]
    const float* w = (const float*)d_in[1];   // [N,K]
    float* out = (float*)d_out;               // [M,N]

    unsigned char* ws = (unsigned char*)d_ws;
    unsigned* amax = (unsigned*)ws;                        // 2 uints
    signed char* aq = (signed char*)(ws + 256);            // M*K int8 (swizzled)
    signed char* wq = aq + (long)M * K;                    // N*K int8 (swizzled)

    hipMemsetAsync(amax, 0, 2 * sizeof(unsigned), stream);
    amax_kernel<<<4096, 256, 0, stream>>>(x, w, amax);
    quant_kernel<<<4096, 256, 0, stream>>>(x, w, aq, wq, amax);

    dim3 grid(M / 128, N / 256);
    gemm_i8_kernel<<<grid, 512, 0, stream>>>(aq, wq, out, amax);
}

// Round 10
// 419.365 us; speedup vs baseline: 1.2864x; 1.1110x over previous
//
#include <hip/hip_runtime.h>

#define FP8_MAX_F 448.0f

static constexpr int M = 8192;   // 4*2048
static constexpr int N = 8192;
static constexpr int K = 4096;

typedef __attribute__((ext_vector_type(4))) int i32x4;

#define AS1 __attribute__((address_space(1)))
#define AS3 __attribute__((address_space(3)))
// Builtin barrier: NO "memory"-clobber asm -> compiler does not pre-drain
// vmcnt/lgkmcnt (the asm-barrier drain was the suspected 43%-plateau cause).
// sched_barrier(0) fences pin instruction placement across it (rule 18/19).
#define BARRIER() do { \
        __builtin_amdgcn_sched_barrier(0); \
        __builtin_amdgcn_s_barrier(); \
        __builtin_amdgcn_sched_barrier(0); \
    } while (0)
#define VMCNT(n)  asm volatile("s_waitcnt vmcnt(" #n ")" ::: "memory")

// ---------------- amax over both tensors (exact, bit-trick atomicMax) --------
__global__ void amax_kernel(const float* __restrict__ x, const float* __restrict__ w,
                            unsigned* __restrict__ out) {
    const long n4x = (long)M * K / 4;
    const long n4t = n4x + (long)N * K / 4;
    unsigned lx = 0u, lw = 0u;
    const long stride = (long)gridDim.x * blockDim.x;
    for (long i = (long)blockIdx.x * blockDim.x + threadIdx.x; i < n4t; i += stride) {
        if (i < n4x) {
            float4 v = ((const float4*)x)[i];
            unsigned a0 = __float_as_uint(v.x) & 0x7fffffffu;
            unsigned a1 = __float_as_uint(v.y) & 0x7fffffffu;
            unsigned a2 = __float_as_uint(v.z) & 0x7fffffffu;
            unsigned a3 = __float_as_uint(v.w) & 0x7fffffffu;
            lx = max(lx, max(max(a0, a1), max(a2, a3)));
        } else {
            float4 v = ((const float4*)w)[i - n4x];
            unsigned a0 = __float_as_uint(v.x) & 0x7fffffffu;
            unsigned a1 = __float_as_uint(v.y) & 0x7fffffffu;
            unsigned a2 = __float_as_uint(v.z) & 0x7fffffffu;
            unsigned a3 = __float_as_uint(v.w) & 0x7fffffffu;
            lw = max(lw, max(max(a0, a1), max(a2, a3)));
        }
    }
    #pragma unroll
    for (int off = 32; off > 0; off >>= 1) {
        lx = max(lx, (unsigned)__shfl_down((int)lx, off, 64));
        lw = max(lw, (unsigned)__shfl_down((int)lw, off, 64));
    }
    __shared__ unsigned smx[4], smw[4];
    if ((threadIdx.x & 63) == 0) { smx[threadIdx.x >> 6] = lx; smw[threadIdx.x >> 6] = lw; }
    __syncthreads();
    if (threadIdx.x == 0) {
        atomicMax(&out[0], max(max(smx[0], smx[1]), max(smx[2], smx[3])));
        atomicMax(&out[1], max(max(smw[0], smw[1]), max(smw[2], smw[3])));
    }
}

// ---------------- quantize both tensors to int8 codes, pre-swizzled layout ---
// Logical code (row r, k) stored with its 16B chunk XOR-permuted within each
// 64B k-group: chunk' = (k>>4)&3 XOR ((r>>1)&3). GEMM stages linearly
// (global_load_lds) and applies the same XOR on ds_read (T2, rule 21).
__device__ __forceinline__ signed char quant1(float v, float s) {
    float f = fminf(fmaxf(v * s, -FP8_MAX_F), FP8_MAX_F);
    return (signed char)(int)rintf(f / FP8_MAX_F * 127.0f);
}

__global__ void quant_kernel(const float* __restrict__ x, const float* __restrict__ w,
                             signed char* __restrict__ qx, signed char* __restrict__ qw,
                             const unsigned* __restrict__ amax_bits) {
    const float ax = fmaxf(__uint_as_float(amax_bits[0]), 1e-12f);
    const float aw = fmaxf(__uint_as_float(amax_bits[1]), 1e-12f);
    const float sxv = FP8_MAX_F / ax;
    const float swv = FP8_MAX_F / aw;
    const long cx = (long)M * K / 16;
    const long ct = cx + (long)N * K / 16;
    const long stride = (long)gridDim.x * blockDim.x;
    for (long ci = (long)blockIdx.x * blockDim.x + threadIdx.x; ci < ct; ci += stride) {
        const float* src; signed char* dst; float s; long c;
        if (ci < cx) { src = x; dst = qx; s = sxv; c = ci; }
        else         { src = w; dst = qw; s = swv; c = ci - cx; }
        const long r = c >> 8;              // K/16 = 256 chunks per row
        const int  cr = (int)(c & 255);
        const float4* in = (const float4*)(src + r * K + cr * 16);
        signed char ob[16];
        #pragma unroll
        for (int j = 0; j < 4; ++j) {
            float4 v = in[j];
            ob[j * 4 + 0] = quant1(v.x, s);
            ob[j * 4 + 1] = quant1(v.y, s);
            ob[j * 4 + 2] = quant1(v.z, s);
            ob[j * 4 + 3] = quant1(v.w, s);
        }
        const int osub = (cr & 3) ^ ((int)(r >> 1) & 3);
        *(int4*)(dst + r * K + ((long)((cr & ~3) + osub)) * 16) = *(const int4*)ob;
    }
}

// ---------------- int8 GEMM: C[m][n] = sum_k A[m][k]*B[n][k] ----------------
// 256x256 tile, BK=64, 512 threads = 8 waves (2M x 4N), wave output 128x64.
// R3 schedule EXACTLY (4-deep circular LDS, frags prefetched 1 tile ahead,
// 4 barriers/tile, counted vmcnt(4), setprio, T2 swizzle) with the ONLY
// change: builtin s_barrier (non-draining) instead of asm s_barrier with
// "memory" clobber (which forces a vmcnt(0)/lgkmcnt(0) drain at EVERY
// barrier -> serializes staging+reads against MFMA; suspected cause of the
// 42-50% MfmaUtil plateau across 7 structural variants).
__global__ __launch_bounds__(512, 2) void gemm_i8_kernel(
    const signed char* __restrict__ Aq, const signed char* __restrict__ Bq,
    float* __restrict__ C, const unsigned* __restrict__ amax_bits)
{
    __shared__ signed char lds[4][2][256 * 64];   // [buf][A/B][row*64 + col]

    const int tid  = threadIdx.x;
    const int wid  = tid >> 6;
    const int lane = tid & 63;
    const int wm = wid >> 2;          // 0..1  (M half)
    const int wn = wid & 3;           // 0..3  (N quarter)
    const int fr = lane & 15;
    const int fq = lane >> 4;

    const long row0 = (long)blockIdx.x * 256;
    const long col0 = (long)blockIdx.y * 256;
    const signed char* Ablk = Aq + row0 * K;
    const signed char* Bblk = Bq + col0 * K;

    // staging: one issue = 512 thr x 16B = 128 rows x 64B (linear LDS dest)
    const long stag_off = (long)(tid >> 2) * K + (long)(tid & 3) * 16;

    // swizzled ds_read offsets
    const int arow = wm * 128 + fr;
    const int aoff = arow * 64 + ((fq ^ ((arow >> 1) & 3)) * 16);
    const int brow = wn * 64 + fr;
    const int boff = brow * 64 + ((fq ^ ((brow >> 1) & 3)) * 16);

    i32x4 acc[8][4] = {};
    i32x4 afR[2][8];      // double-buffered A fragments (tile parity)
    i32x4 bR[2][4];       // double-buffered B fragments

#define STAGE_A(st, bi) do { \
        const signed char* g = Ablk + (long)(st) * 64 + stag_off; \
        __builtin_amdgcn_global_load_lds((const AS1 void*)g, \
            (AS3 void*)(&lds[bi][0][0] + wid * 1024), 16, 0, 0); \
        __builtin_amdgcn_global_load_lds((const AS1 void*)(g + 128L * K), \
            (AS3 void*)(&lds[bi][0][0] + 8192 + wid * 1024), 16, 0, 0); \
    } while (0)

#define STAGE_B(st, bi) do { \
        const signed char* g = Bblk + (long)(st) * 64 + stag_off; \
        __builtin_amdgcn_global_load_lds((const AS1 void*)g, \
            (AS3 void*)(&lds[bi][1][0] + wid * 1024), 16, 0, 0); \
        __builtin_amdgcn_global_load_lds((const AS1 void*)(g + 128L * K), \
            (AS3 void*)(&lds[bi][1][0] + 8192 + wid * 1024), 16, 0, 0); \
    } while (0)

    // prologue: stage tiles 0,1,2 (12 issues); drain to 4 -> tiles 0,1 resident
    STAGE_A(0, 0); STAGE_B(0, 0);
    STAGE_A(1, 1); STAGE_B(1, 1);
    STAGE_A(2, 2); STAGE_B(2, 2);
    VMCNT(4);
    BARRIER();
    #pragma unroll
    for (int mi = 0; mi < 8; ++mi)
        afR[0][mi] = *(const i32x4*)(&lds[0][0][0] + aoff + mi * 1024);
    #pragma unroll
    for (int ni = 0; ni < 4; ++ni)
        bR[0][ni] = *(const i32x4*)(&lds[0][1][0] + boff + ni * 1024);

    // Per tile t (2 phases):
    //  A: read afN(t+1) [8 ds], stage A((t+3)&63), bar, MFMA afC x bC[0,1], bar
    //  B: read bN(t+1)  [4 ds], stage B((t+3)&63), vmcnt(4), bar,
    //     MFMA afC x bC[2,3], bar
#define TILE_BODY(t, CUR, NXT) do { \
        const signed char* la = &lds[((t) + 1) & 3][0][0]; \
        const signed char* lb = &lds[((t) + 1) & 3][1][0]; \
        _Pragma("unroll") \
        for (int mi = 0; mi < 8; ++mi) \
            afR[NXT][mi] = *(const i32x4*)(la + aoff + mi * 1024); \
        STAGE_A(((t) + 3) & 63, ((t) + 3) & 3); \
        BARRIER(); \
        __builtin_amdgcn_s_setprio(1); \
        _Pragma("unroll") \
        for (int mi = 0; mi < 8; ++mi) { \
            acc[mi][0] = __builtin_amdgcn_mfma_i32_16x16x64_i8(afR[CUR][mi], bR[CUR][0], acc[mi][0], 0, 0, 0); \
            acc[mi][1] = __builtin_amdgcn_mfma_i32_16x16x64_i8(afR[CUR][mi], bR[CUR][1], acc[mi][1], 0, 0, 0); \
        } \
        __builtin_amdgcn_s_setprio(0); \
        BARRIER(); \
        _Pragma("unroll") \
        for (int ni = 0; ni < 4; ++ni) \
            bR[NXT][ni] = *(const i32x4*)(lb + boff + ni * 1024); \
        STAGE_B(((t) + 3) & 63, ((t) + 3) & 3); \
        VMCNT(4); \
        BARRIER(); \
        __builtin_amdgcn_s_setprio(1); \
        _Pragma("unroll") \
        for (int mi = 0; mi < 8; ++mi) { \
            acc[mi][2] = __builtin_amdgcn_mfma_i32_16x16x64_i8(afR[CUR][mi], bR[CUR][2], acc[mi][2], 0, 0, 0); \
            acc[mi][3] = __builtin_amdgcn_mfma_i32_16x16x64_i8(afR[CUR][mi], bR[CUR][3], acc[mi][3], 0, 0, 0); \
        } \
        __builtin_amdgcn_s_setprio(0); \
        BARRIER(); \
    } while (0)

    #pragma unroll 1
    for (int t = 0; t < 64; t += 2) {
        TILE_BODY(t, 0, 1);
        TILE_BODY(t + 1, 1, 0);
    }

#undef TILE_BODY
#undef STAGE_B
#undef STAGE_A

    const float ax = fmaxf(__uint_as_float(amax_bits[0]), 1e-12f);
    const float aw = fmaxf(__uint_as_float(amax_bits[1]), 1e-12f);
    const float factor = ax * aw * (1.0f / (127.0f * 127.0f));

    #pragma unroll
    for (int mi = 0; mi < 8; ++mi) {
        #pragma unroll
        for (int ni = 0; ni < 4; ++ni) {
            const long col = col0 + wn * 64 + ni * 16 + fr;
            #pragma unroll
            for (int j = 0; j < 4; ++j) {
                const long row = row0 + wm * 128 + mi * 16 + fq * 4 + j;
                C[row * N + col] = (float)acc[mi][ni][j] * factor;
            }
        }
    }
}

extern "C" void kernel_launch(void* const* d_in, const int* in_sizes, int n_in,
                              void* d_out, int out_size, void* d_ws, size_t ws_size,
                              hipStream_t stream) {
    const float* x = (const float*)d_in[0];   // [4,2048,4096] -> [M,K]
    const float* w = (const float*)d_in[1];   // [N,K]
    float* out = (float*)d_out;               // [M,N]

    unsigned char* ws = (unsigned char*)d_ws;
    unsigned* amax = (unsigned*)ws;                        // 2 uints
    signed char* aq = (signed char*)(ws + 256);            // M*K int8 (swizzled)
    signed char* wq = aq + (long)M * K;                    // N*K int8 (swizzled)

    hipMemsetAsync(amax, 0, 2 * sizeof(unsigned), stream);
    amax_kernel<<<2048, 256, 0, stream>>>(x, w, amax);
    quant_kernel<<<4096, 256, 0, stream>>>(x, w, aq, wq, amax);

    dim3 grid(M / 256, N / 256);
    gemm_i8_kernel<<<grid, 512, 0, stream>>>(aq, wq, out, amax);
}